// Round 1
// baseline (284.149 us; speedup 1.0000x reference)
//
#include <hip/hip_runtime.h>
#include <hip/hip_bf16.h>

// B=2, N=2048, D=1024, H=16, DH=64. f32 in / f32 out, bf16 MFMA internally.

typedef unsigned short u16;
typedef __bf16 bf16x8 __attribute__((ext_vector_type(8)));
typedef float  f32x4  __attribute__((ext_vector_type(4)));
typedef unsigned short u16x4 __attribute__((ext_vector_type(4)));

#define DEV __device__ __forceinline__

DEV u16 f2bf(float f) {
  unsigned u = __builtin_bit_cast(unsigned, f);
  return (u16)((u + 0x7FFFu + ((u >> 16) & 1u)) >> 16);  // RNE
}

DEV f32x4 mfma16(bf16x8 a, bf16x8 b, f32x4 c) {
  return __builtin_amdgcn_mfma_f32_16x16x32_bf16(a, b, c, 0, 0, 0);
}

template <typename T>
DEV void gload16(const T* g, T* l) {  // global -> LDS, 16B per lane, dest = base + lane*16
  __builtin_amdgcn_global_load_lds((__attribute__((address_space(1))) void*)g,
                                   (__attribute__((address_space(3))) void*)l, 16, 0, 0);
}

// ---------------- prep kernels ----------------

__global__ __launch_bounds__(256) void cvt_x(const float* __restrict__ x,
                                             u16* __restrict__ xb) {
  int idx = (blockIdx.x * 256 + threadIdx.x) * 4;
  float4 v = *(const float4*)(x + idx);
  u16x4 u = { f2bf(v.x), f2bf(v.y), f2bf(v.z), f2bf(v.w) };
  *(u16x4*)(xb + idx) = u;
}

// dst[c][r] = bf16(src[r][c] * (c < scaleLim ? 0.125 : 1));  src [R][C], dst [C][R]
__global__ __launch_bounds__(256) void wtrans(const float* __restrict__ src,
                                              u16* __restrict__ dst,
                                              int R, int C, int scaleLim) {
  __shared__ u16 T[64][72];
  const int tid = threadIdx.x;
  const int c0 = blockIdx.x * 64, r0 = blockIdx.y * 64;
  const int cl = tid & 63;
  const float scale = (c0 + cl < scaleLim) ? 0.125f : 1.0f;
#pragma unroll
  for (int i = 0; i < 16; ++i) {
    int r = (tid >> 6) * 16 + i;
    T[cl][r] = f2bf(src[(size_t)(r0 + r) * C + c0 + cl] * scale);
  }
  __syncthreads();
#pragma unroll
  for (int i = 0; i < 16; ++i) {
    int cc = (tid >> 6) * 16 + i;
    dst[(size_t)(c0 + cc) * R + r0 + cl] = T[cc][cl];
  }
}

// V part of qkv -> vt[b][h][d][n]   (kv-contiguous for the PV B-operand)
__global__ __launch_bounds__(256) void vtrans(const u16* __restrict__ qkv,
                                              u16* __restrict__ vtout) {
  __shared__ u16 T[64][72];
  const int tid = threadIdx.x;
  const int n0 = blockIdx.x * 64;
  const int h = blockIdx.y, b = blockIdx.z;
  const int dl = tid & 63;
#pragma unroll
  for (int i = 0; i < 16; ++i) {
    int n = (tid >> 6) * 16 + i;
    T[dl][n] = qkv[(size_t)(b * 2048 + n0 + n) * 3072 + 2048 + h * 64 + dl];
  }
  __syncthreads();
#pragma unroll
  for (int i = 0; i < 16; ++i) {
    int d = (tid >> 6) * 16 + i;
    vtout[(size_t)((b * 16 + h) * 64 + d) * 2048 + n0 + dl] = T[d][dl];
  }
}

// ---------------- GEMM: C[M,N] = A[M,1024] * Bt[N,1024]^T ----------------
// 128x128 tile, BK=64, 4 waves (2x2 of 64x64), global_load_lds w=16,
// XOR-swizzled LDS (byte ^ ((row&7)<<4)) to kill the stride-128B bank conflict.

__global__ __launch_bounds__(256) void gemm_bf16(const u16* __restrict__ A,
                                                 const u16* __restrict__ Bt,
                                                 u16* __restrict__ Cb,
                                                 float* __restrict__ Cf, int N) {
  __shared__ __align__(16) u16 lA[128 * 64];
  __shared__ __align__(16) u16 lB[128 * 64];
  const int tid = threadIdx.x;
  const int lane = tid & 63, w = tid >> 6;
  const int g = lane >> 4, r16 = lane & 15;
  const int wm = w >> 1, wn = w & 1;
  const int m0 = blockIdx.y * 128, n0 = blockIdx.x * 128;

  const f32x4 z4 = {0.f, 0.f, 0.f, 0.f};
  f32x4 acc[4][4];
#pragma unroll
  for (int m = 0; m < 4; ++m)
#pragma unroll
    for (int n = 0; n < 4; ++n) acc[m][n] = z4;

  for (int kt = 0; kt < 16; ++kt) {
    const int kbase = kt * 64;
#pragma unroll
    for (int issue = 0; issue < 4; ++issue) {
      int i = issue * 256 + tid;
      int r = i >> 3, jp = (i & 7) ^ (r & 7);  // swizzled source chunk
      u16* dst = (u16*)((char*)nullptr);
      (void)dst;
      gload16(A + (size_t)(m0 + r) * 1024 + kbase + jp * 8,
              lA + (size_t)(issue * 256 + (tid & ~63)) * 8);
      gload16(Bt + (size_t)(n0 + r) * 1024 + kbase + jp * 8,
              lB + (size_t)(issue * 256 + (tid & ~63)) * 8);
    }
    __syncthreads();
#pragma unroll
    for (int kk = 0; kk < 2; ++kk) {
      bf16x8 a[4], b[4];
#pragma unroll
      for (int m = 0; m < 4; ++m) {
        int row = wm * 64 + m * 16 + r16;
        int off = row * 128 + ((kk * 64 + g * 16) ^ ((r16 & 7) << 4));
        a[m] = *(const bf16x8*)((const char*)lA + off);
      }
#pragma unroll
      for (int n = 0; n < 4; ++n) {
        int row = wn * 64 + n * 16 + r16;
        int off = row * 128 + ((kk * 64 + g * 16) ^ ((r16 & 7) << 4));
        b[n] = *(const bf16x8*)((const char*)lB + off);
      }
#pragma unroll
      for (int m = 0; m < 4; ++m)
#pragma unroll
        for (int n = 0; n < 4; ++n) acc[m][n] = mfma16(a[m], b[n], acc[m][n]);
    }
    __syncthreads();
  }
  // epilogue: C row=(lane>>4)*4+j, col=lane&15 per 16x16 fragment [m89]
#pragma unroll
  for (int m = 0; m < 4; ++m)
#pragma unroll
    for (int n = 0; n < 4; ++n) {
      int col = n0 + wn * 64 + n * 16 + r16;
#pragma unroll
      for (int j = 0; j < 4; ++j) {
        int row = m0 + wm * 64 + m * 16 + g * 4 + j;
        if (Cb) Cb[(size_t)row * N + col] = f2bf(acc[m][n][j]);
        else    Cf[(size_t)row * N + col] = acc[m][n][j];
      }
    }
}

// ---------------- fused causal flash attention ----------------
// block = (b, h, qt): 64 q-rows; 4 waves x 16 q-rows each. KV tiles of 64.
// S^T never materialized: S frags C-layout; P restaged via per-wave LDS.

__global__ __launch_bounds__(256) void attn_fused(const u16* __restrict__ qkv,
                                                  const u16* __restrict__ vt,
                                                  u16* __restrict__ ao) {
  __shared__ __align__(16) u16 lK[64 * 64];
  __shared__ __align__(16) u16 lV[64 * 64];
  __shared__ __align__(16) u16 lP[4][16 * 64];
  const int tid = threadIdx.x;
  const int lane = tid & 63, w = tid >> 6;
  const int g = lane >> 4, r16 = lane & 15;
  const int qt = 31 - (int)blockIdx.x;  // heavy blocks first (causal triangle)
  const int h = blockIdx.y, b = blockIdx.z;
  const int q0w = qt * 64 + w * 16;

  // Q fragments held in registers for the whole block (scale folded into wqkvT)
  bf16x8 aq[2];
  {
    const u16* qrow = qkv + (size_t)(b * 2048 + q0w + r16) * 3072 + h * 64;
    aq[0] = *(const bf16x8*)(qrow + g * 8);
    aq[1] = *(const bf16x8*)(qrow + 32 + g * 8);
  }

  const f32x4 z4 = {0.f, 0.f, 0.f, 0.f};
  f32x4 o[4];
  float mrun[4], lrun[4];
#pragma unroll
  for (int n = 0; n < 4; ++n) o[n] = z4;
#pragma unroll
  for (int j = 0; j < 4; ++j) { mrun[j] = -INFINITY; lrun[j] = 0.f; }

  const int ntiles = qt + 1;
  for (int t = 0; t < ntiles; ++t) {
    const int kv0 = t * 64;
#pragma unroll
    for (int issue = 0; issue < 2; ++issue) {
      int i = issue * 256 + tid;
      int r = i >> 3, jp = (i & 7) ^ (r & 7);
      gload16(qkv + (size_t)(b * 2048 + kv0 + r) * 3072 + 1024 + h * 64 + jp * 8,
              lK + (size_t)(issue * 256 + (tid & ~63)) * 8);
      gload16(vt + (size_t)((b * 16 + h) * 64 + r) * 2048 + kv0 + jp * 8,
              lV + (size_t)(issue * 256 + (tid & ~63)) * 8);
    }
    __syncthreads();

    // S = Q K^T : 16q x 64kv per wave
    f32x4 s[4];
#pragma unroll
    for (int f = 0; f < 4; ++f) s[f] = z4;
#pragma unroll
    for (int kk = 0; kk < 2; ++kk) {
#pragma unroll
      for (int f = 0; f < 4; ++f) {
        int row = f * 16 + r16;
        int off = row * 128 + ((kk * 64 + g * 16) ^ ((r16 & 7) << 4));
        bf16x8 bk = *(const bf16x8*)((const char*)lK + off);
        s[f] = mfma16(aq[kk], bk, s[f]);
      }
    }
    // causal mask (only the diagonal region needs it)
    if (kv0 + 63 > q0w) {
#pragma unroll
      for (int f = 0; f < 4; ++f)
#pragma unroll
        for (int j = 0; j < 4; ++j) {
          int q = q0w + g * 4 + j;
          int kv = kv0 + f * 16 + r16;
          if (kv > q) s[f][j] = -3.0e38f;
        }
    }
    // online softmax; row j of lane = q-row g*4+j; cols spread over 16 lanes + 4 frags
    float mx[4], sm[4];
#pragma unroll
    for (int j = 0; j < 4; ++j)
      mx[j] = fmaxf(fmaxf(s[0][j], s[1][j]), fmaxf(s[2][j], s[3][j]));
#pragma unroll
    for (int off = 1; off < 16; off <<= 1)
#pragma unroll
      for (int j = 0; j < 4; ++j) mx[j] = fmaxf(mx[j], __shfl_xor(mx[j], off));
    float corr[4];
#pragma unroll
    for (int j = 0; j < 4; ++j) {
      float mn = fmaxf(mrun[j], mx[j]);
      corr[j] = __expf(mrun[j] - mn);
      mrun[j] = mn;
    }
#pragma unroll
    for (int f = 0; f < 4; ++f)
#pragma unroll
      for (int j = 0; j < 4; ++j) s[f][j] = __expf(s[f][j] - mrun[j]);
#pragma unroll
    for (int j = 0; j < 4; ++j) sm[j] = s[0][j] + s[1][j] + s[2][j] + s[3][j];
#pragma unroll
    for (int off = 1; off < 16; off <<= 1)
#pragma unroll
      for (int j = 0; j < 4; ++j) sm[j] += __shfl_xor(sm[j], off);
#pragma unroll
    for (int j = 0; j < 4; ++j) lrun[j] = lrun[j] * corr[j] + sm[j];
#pragma unroll
    for (int n = 0; n < 4; ++n)
#pragma unroll
      for (int j = 0; j < 4; ++j) o[n][j] *= corr[j];

    // P -> per-wave LDS (swizzled), then PV
    u16* lp = lP[w];
#pragma unroll
    for (int f = 0; f < 4; ++f)
#pragma unroll
      for (int j = 0; j < 4; ++j) {
        int row = g * 4 + j;
        int cb = (f * 16 + r16) * 2;
        *(u16*)((char*)lp + row * 128 + (cb ^ ((row & 7) << 4))) = f2bf(s[f][j]);
      }
#pragma unroll
    for (int kk = 0; kk < 2; ++kk) {
      int offp = r16 * 128 + ((kk * 64 + g * 16) ^ ((r16 & 7) << 4));
      bf16x8 ap = *(const bf16x8*)((const char*)lp + offp);
#pragma unroll
      for (int n = 0; n < 4; ++n) {
        int row = n * 16 + r16;
        int off = row * 128 + ((kk * 64 + g * 16) ^ ((r16 & 7) << 4));
        bf16x8 bv = *(const bf16x8*)((const char*)lV + off);
        o[n] = mfma16(ap, bv, o[n]);
      }
    }
    __syncthreads();
  }
  // epilogue -> ao[b*2048+q][h*64+d] bf16
#pragma unroll
  for (int n = 0; n < 4; ++n) {
    int col = h * 64 + n * 16 + r16;
#pragma unroll
    for (int j = 0; j < 4; ++j) {
      int row = b * 2048 + q0w + g * 4 + j;
      ao[(size_t)row * 1024 + col] = f2bf(o[n][j] * (1.f / lrun[j]));
    }
  }
}

// ---------------- launch ----------------

extern "C" void kernel_launch(void* const* d_in, const int* in_sizes, int n_in,
                              void* d_out, int out_size, void* d_ws, size_t ws_size,
                              hipStream_t stream) {
  const float* x     = (const float*)d_in[0];
  // d_in[1] = attn_mask: causal tril, implemented analytically — unused.
  const float* w_qkv = (const float*)d_in[2];
  const float* w_out = (const float*)d_in[3];
  float* out = (float*)d_out;

  u16* ws = (u16*)d_ws;
  u16* x_bf  = ws;                               // 4096*1024           (4M)
  u16* wqkvT = x_bf + (size_t)4096 * 1024;       // 3072*1024           (3M)
  u16* woutT = wqkvT + (size_t)3072 * 1024;      // 1024*1024           (1M)
  u16* qkv   = woutT + (size_t)1024 * 1024;      // 4096*3072           (12M)
  u16* ao    = qkv + (size_t)4096 * 3072;        // 4096*1024           (4M)
  u16* vtb   = x_bf;                             // 2048*2048, aliases x_bf (dead after GEMM1)

  cvt_x<<<4096, 256, 0, stream>>>(x, x_bf);
  wtrans<<<dim3(48, 16), 256, 0, stream>>>(w_qkv, wqkvT, 1024, 3072, 1024);  // fold q-scale
  wtrans<<<dim3(16, 16), 256, 0, stream>>>(w_out, woutT, 1024, 1024, 0);
  gemm_bf16<<<dim3(24, 32), 256, 0, stream>>>(x_bf, wqkvT, qkv, nullptr, 3072);
  vtrans<<<dim3(32, 16, 2), 256, 0, stream>>>(qkv, vtb);
  attn_fused<<<dim3(32, 16, 2), 256, 0, stream>>>(qkv, vtb, ao);
  gemm_bf16<<<dim3(8, 32), 256, 0, stream>>>(ao, woutT, nullptr, out, 1024);
}

// Round 2
// 259.420 us; speedup vs baseline: 1.0953x; 1.0953x over previous
//
#include <hip/hip_runtime.h>
#include <hip/hip_bf16.h>

// B=2, N=2048, D=1024, H=16, DH=64. f32 in / f32 out, bf16 MFMA internally.

typedef unsigned short u16;
typedef __bf16 bf16x8 __attribute__((ext_vector_type(8)));
typedef float  f32x4  __attribute__((ext_vector_type(4)));
typedef unsigned short u16x4 __attribute__((ext_vector_type(4)));

#define DEV __device__ __forceinline__

DEV u16 f2bf(float f) {
  unsigned u = __builtin_bit_cast(unsigned, f);
  return (u16)((u + 0x7FFFu + ((u >> 16) & 1u)) >> 16);  // RNE
}

DEV f32x4 mfma16(bf16x8 a, bf16x8 b, f32x4 c) {
  return __builtin_amdgcn_mfma_f32_16x16x32_bf16(a, b, c, 0, 0, 0);
}

template <typename T>
DEV void gload16(const T* g, T* l) {  // global -> LDS, 16B per lane, dest = base + lane*16
  __builtin_amdgcn_global_load_lds((__attribute__((address_space(1))) void*)g,
                                   (__attribute__((address_space(3))) void*)l, 16, 0, 0);
}

// ---------------- prep kernels ----------------

__global__ __launch_bounds__(256) void cvt_x(const float* __restrict__ x,
                                             u16* __restrict__ xb) {
  int idx = (blockIdx.x * 256 + threadIdx.x) * 4;
  float4 v = *(const float4*)(x + idx);
  u16x4 u = { f2bf(v.x), f2bf(v.y), f2bf(v.z), f2bf(v.w) };
  *(u16x4*)(xb + idx) = u;
}

// dst[c][r] = bf16(src[r][c] * (c < scaleLim ? 0.125 : 1));  src [R][C], dst [C][R]
__global__ __launch_bounds__(256) void wtrans(const float* __restrict__ src,
                                              u16* __restrict__ dst,
                                              int R, int C, int scaleLim) {
  __shared__ u16 T[64][72];
  const int tid = threadIdx.x;
  const int c0 = blockIdx.x * 64, r0 = blockIdx.y * 64;
  const int cl = tid & 63;
  const float scale = (c0 + cl < scaleLim) ? 0.125f : 1.0f;
#pragma unroll
  for (int i = 0; i < 16; ++i) {
    int r = (tid >> 6) * 16 + i;
    T[cl][r] = f2bf(src[(size_t)(r0 + r) * C + c0 + cl] * scale);
  }
  __syncthreads();
#pragma unroll
  for (int i = 0; i < 16; ++i) {
    int cc = (tid >> 6) * 16 + i;
    dst[(size_t)(c0 + cc) * R + r0 + cl] = T[cc][cl];
  }
}

// V part of qkv -> vt[b][h][d][n]   (kv-contiguous for the PV B-operand)
__global__ __launch_bounds__(256) void vtrans(const u16* __restrict__ qkv,
                                              u16* __restrict__ vtout) {
  __shared__ u16 T[64][72];
  const int tid = threadIdx.x;
  const int n0 = blockIdx.x * 64;
  const int h = blockIdx.y, b = blockIdx.z;
  const int dl = tid & 63;
#pragma unroll
  for (int i = 0; i < 16; ++i) {
    int n = (tid >> 6) * 16 + i;
    T[dl][n] = qkv[(size_t)(b * 2048 + n0 + n) * 3072 + 2048 + h * 64 + dl];
  }
  __syncthreads();
#pragma unroll
  for (int i = 0; i < 16; ++i) {
    int d = (tid >> 6) * 16 + i;
    vtout[(size_t)((b * 16 + h) * 64 + d) * 2048 + n0 + dl] = T[d][dl];
  }
}

// ---------------- GEMM: C[M,N] = A[M,1024] * Bt[N,1024]^T ----------------
// 128x128 tile, BK=64, 4 waves (2x2 of 64x64), global_load_lds w=16,
// XOR-swizzled LDS (byte ^ ((row&7)<<4)) to kill the stride-128B bank conflict.

__global__ __launch_bounds__(256) void gemm_bf16(const u16* __restrict__ A,
                                                 const u16* __restrict__ Bt,
                                                 u16* __restrict__ Cb,
                                                 float* __restrict__ Cf, int N) {
  __shared__ __align__(16) u16 lA[128 * 64];
  __shared__ __align__(16) u16 lB[128 * 64];
  const int tid = threadIdx.x;
  const int lane = tid & 63, w = tid >> 6;
  const int g = lane >> 4, r16 = lane & 15;
  const int wm = w >> 1, wn = w & 1;
  const int m0 = blockIdx.y * 128, n0 = blockIdx.x * 128;

  const f32x4 z4 = {0.f, 0.f, 0.f, 0.f};
  f32x4 acc[4][4];
#pragma unroll
  for (int m = 0; m < 4; ++m)
#pragma unroll
    for (int n = 0; n < 4; ++n) acc[m][n] = z4;

  for (int kt = 0; kt < 16; ++kt) {
    const int kbase = kt * 64;
#pragma unroll
    for (int issue = 0; issue < 4; ++issue) {
      int i = issue * 256 + tid;
      int r = i >> 3, jp = (i & 7) ^ (r & 7);  // swizzled source chunk
      gload16(A + (size_t)(m0 + r) * 1024 + kbase + jp * 8,
              lA + (size_t)(issue * 256 + (tid & ~63)) * 8);
      gload16(Bt + (size_t)(n0 + r) * 1024 + kbase + jp * 8,
              lB + (size_t)(issue * 256 + (tid & ~63)) * 8);
    }
    __syncthreads();
#pragma unroll
    for (int kk = 0; kk < 2; ++kk) {
      bf16x8 a[4], b[4];
#pragma unroll
      for (int m = 0; m < 4; ++m) {
        int row = wm * 64 + m * 16 + r16;
        int off = row * 128 + ((kk * 64 + g * 16) ^ ((r16 & 7) << 4));
        a[m] = *(const bf16x8*)((const char*)lA + off);
      }
#pragma unroll
      for (int n = 0; n < 4; ++n) {
        int row = wn * 64 + n * 16 + r16;
        int off = row * 128 + ((kk * 64 + g * 16) ^ ((r16 & 7) << 4));
        b[n] = *(const bf16x8*)((const char*)lB + off);
      }
#pragma unroll
      for (int m = 0; m < 4; ++m)
#pragma unroll
        for (int n = 0; n < 4; ++n) acc[m][n] = mfma16(a[m], b[n], acc[m][n]);
    }
    __syncthreads();
  }
  // epilogue: C row=(lane>>4)*4+j, col=lane&15 per 16x16 fragment [m89]
#pragma unroll
  for (int m = 0; m < 4; ++m)
#pragma unroll
    for (int n = 0; n < 4; ++n) {
      int col = n0 + wn * 64 + n * 16 + r16;
#pragma unroll
      for (int j = 0; j < 4; ++j) {
        int row = m0 + wm * 64 + m * 16 + g * 4 + j;
        if (Cb) Cb[(size_t)row * N + col] = f2bf(acc[m][n][j]);
        else    Cf[(size_t)row * N + col] = acc[m][n][j];
      }
    }
}

// ---------------- fused causal flash attention ----------------
// QBLK=128 (8 waves x 16 q-rows), KVBLK=64, double-buffered K/V in LDS with
// one-tile-ahead prefetch (loads overlap the full compute phase; the single
// __syncthreads per tile drains them). XCD-swizzled 1D grid: all 16 q-blocks
// of one (b,h) land on one XCD's L2.

__global__ __launch_bounds__(512) void attn_fused(const u16* __restrict__ qkv,
                                                  const u16* __restrict__ vt,
                                                  u16* __restrict__ ao) {
  __shared__ __align__(16) u16 lK[2][64 * 64];
  __shared__ __align__(16) u16 lV[2][64 * 64];
  __shared__ __align__(16) u16 lP[8][16 * 64];
  const int tid = threadIdx.x;
  const int lane = tid & 63, w = tid >> 6;
  const int g = lane >> 4, r16 = lane & 15;

  // decode XCD-swizzled flat id: xcd = flat&7 owns 4 (b,h) groups x 16 qt
  const int flat = (int)blockIdx.x;
  const int xcd = flat & 7, slot = flat >> 3;
  const int grp = xcd * 4 + (slot >> 4);   // b*16+h
  const int qt = 15 - (slot & 15);         // heavy-first
  const int b = grp >> 4, h = grp & 15;
  const int q0w = qt * 128 + w * 16;

  // Q fragments in registers for the whole block (scale folded into wqkvT)
  bf16x8 aq[2];
  {
    const u16* qrow = qkv + (size_t)(b * 2048 + q0w + r16) * 3072 + h * 64;
    aq[0] = *(const bf16x8*)(qrow + g * 8);
    aq[1] = *(const bf16x8*)(qrow + 32 + g * 8);
  }

  const int r = tid >> 3, jp = (tid & 7) ^ (r & 7);  // staging decomposition
  const u16* ksrc = qkv + (size_t)(b * 2048 + r) * 3072 + 1024 + h * 64 + jp * 8;
  const u16* vsrc = vt + (size_t)((b * 16 + h) * 64 + r) * 2048 + jp * 8;
  const size_t ldst = (size_t)(tid & ~63) * 8;

  const f32x4 z4 = {0.f, 0.f, 0.f, 0.f};
  f32x4 o[4];
  float mrun[4], lrun[4];
#pragma unroll
  for (int n = 0; n < 4; ++n) o[n] = z4;
#pragma unroll
  for (int j = 0; j < 4; ++j) { mrun[j] = -INFINITY; lrun[j] = 0.f; }

  const int nt = 2 * qt + 2;
  // prologue: stage tile 0 into buf 0
  gload16(ksrc, lK[0] + ldst);
  gload16(vsrc, lV[0] + ldst);
  __syncthreads();

  int cur = 0;
  for (int t = 0; t < nt; ++t) {
    const int kv0 = t * 64;
    if (t + 1 < nt) {  // prefetch next tile into the other buffer
      gload16(ksrc + (size_t)(t + 1) * 64 * 3072, lK[cur ^ 1] + ldst);
      gload16(vsrc + (size_t)(t + 1) * 64, lV[cur ^ 1] + ldst);
    }
    if (kv0 <= q0w + 15) {  // wave has unmasked columns in this tile
      // S = Q K^T : 16q x 64kv for this wave
      f32x4 s[4];
#pragma unroll
      for (int f = 0; f < 4; ++f) s[f] = z4;
#pragma unroll
      for (int kk = 0; kk < 2; ++kk) {
#pragma unroll
        for (int f = 0; f < 4; ++f) {
          int row = f * 16 + r16;
          int off = row * 128 + ((kk * 64 + g * 16) ^ ((r16 & 7) << 4));
          bf16x8 bk = *(const bf16x8*)((const char*)lK[cur] + off);
          s[f] = mfma16(aq[kk], bk, s[f]);
        }
      }
      if (kv0 + 63 > q0w) {  // diagonal region: causal mask
#pragma unroll
        for (int f = 0; f < 4; ++f)
#pragma unroll
          for (int j = 0; j < 4; ++j) {
            int q = q0w + g * 4 + j;
            int kv = kv0 + f * 16 + r16;
            if (kv > q) s[f][j] = -3.0e38f;
          }
      }
      // online softmax; lane row j = q-row g*4+j; cols over 16 lanes x 4 frags
      float mx[4], sm[4];
#pragma unroll
      for (int j = 0; j < 4; ++j)
        mx[j] = fmaxf(fmaxf(s[0][j], s[1][j]), fmaxf(s[2][j], s[3][j]));
#pragma unroll
      for (int off = 1; off < 16; off <<= 1)
#pragma unroll
        for (int j = 0; j < 4; ++j) mx[j] = fmaxf(mx[j], __shfl_xor(mx[j], off));
      float corr[4];
#pragma unroll
      for (int j = 0; j < 4; ++j) {
        float mn = fmaxf(mrun[j], mx[j]);
        corr[j] = __expf(mrun[j] - mn);
        mrun[j] = mn;
      }
#pragma unroll
      for (int f = 0; f < 4; ++f)
#pragma unroll
        for (int j = 0; j < 4; ++j) s[f][j] = __expf(s[f][j] - mrun[j]);
#pragma unroll
      for (int j = 0; j < 4; ++j) sm[j] = s[0][j] + s[1][j] + s[2][j] + s[3][j];
#pragma unroll
      for (int off = 1; off < 16; off <<= 1)
#pragma unroll
        for (int j = 0; j < 4; ++j) sm[j] += __shfl_xor(sm[j], off);
#pragma unroll
      for (int j = 0; j < 4; ++j) lrun[j] = lrun[j] * corr[j] + sm[j];
#pragma unroll
      for (int n = 0; n < 4; ++n)
#pragma unroll
        for (int j = 0; j < 4; ++j) o[n][j] *= corr[j];

      // P -> per-wave LDS (swizzled), then PV
      u16* lp = lP[w];
#pragma unroll
      for (int f = 0; f < 4; ++f)
#pragma unroll
        for (int j = 0; j < 4; ++j) {
          int row = g * 4 + j;
          int cb = (f * 16 + r16) * 2;
          *(u16*)((char*)lp + row * 128 + (cb ^ ((row & 7) << 4))) = f2bf(s[f][j]);
        }
#pragma unroll
      for (int kk = 0; kk < 2; ++kk) {
        int offp = r16 * 128 + ((kk * 64 + g * 16) ^ ((r16 & 7) << 4));
        bf16x8 ap = *(const bf16x8*)((const char*)lp + offp);
#pragma unroll
        for (int n = 0; n < 4; ++n) {
          int row = n * 16 + r16;
          int off = row * 128 + ((kk * 64 + g * 16) ^ ((r16 & 7) << 4));
          bf16x8 bv = *(const bf16x8*)((const char*)lV[cur] + off);
          o[n] = mfma16(ap, bv, o[n]);
        }
      }
    }
    __syncthreads();  // drains the prefetch (vmcnt 0) + protects buf reuse
    cur ^= 1;
  }
  // epilogue -> ao[b*2048+q][h*64+d] bf16
#pragma unroll
  for (int n = 0; n < 4; ++n) {
    int col = h * 64 + n * 16 + r16;
#pragma unroll
    for (int j = 0; j < 4; ++j) {
      int row = b * 2048 + q0w + g * 4 + j;
      ao[(size_t)row * 1024 + col] = f2bf(o[n][j] * (1.f / lrun[j]));
    }
  }
}

// ---------------- launch ----------------

extern "C" void kernel_launch(void* const* d_in, const int* in_sizes, int n_in,
                              void* d_out, int out_size, void* d_ws, size_t ws_size,
                              hipStream_t stream) {
  const float* x     = (const float*)d_in[0];
  // d_in[1] = attn_mask: causal tril, implemented analytically — unused.
  const float* w_qkv = (const float*)d_in[2];
  const float* w_out = (const float*)d_in[3];
  float* out = (float*)d_out;

  u16* ws = (u16*)d_ws;
  u16* x_bf  = ws;                               // 4096*1024           (4M)
  u16* wqkvT = x_bf + (size_t)4096 * 1024;       // 3072*1024           (3M)
  u16* woutT = wqkvT + (size_t)3072 * 1024;      // 1024*1024           (1M)
  u16* qkv   = woutT + (size_t)1024 * 1024;      // 4096*3072           (12M)
  u16* ao    = qkv + (size_t)4096 * 3072;        // 4096*1024           (4M)
  u16* vtb   = x_bf;                             // 2048*2048, aliases x_bf (dead after GEMM1)

  cvt_x<<<4096, 256, 0, stream>>>(x, x_bf);
  wtrans<<<dim3(48, 16), 256, 0, stream>>>(w_qkv, wqkvT, 1024, 3072, 1024);  // fold q-scale
  wtrans<<<dim3(16, 16), 256, 0, stream>>>(w_out, woutT, 1024, 1024, 0);
  gemm_bf16<<<dim3(24, 32), 256, 0, stream>>>(x_bf, wqkvT, qkv, nullptr, 3072);
  vtrans<<<dim3(32, 16, 2), 256, 0, stream>>>(qkv, vtb);
  attn_fused<<<512, 512, 0, stream>>>(qkv, vtb, ao);
  gemm_bf16<<<dim3(8, 32), 256, 0, stream>>>(ao, woutT, nullptr, out, 1024);
}

// Round 5
// 243.413 us; speedup vs baseline: 1.1674x; 1.0658x over previous
//
#include <hip/hip_runtime.h>
#include <hip/hip_bf16.h>

// B=2, N=2048, D=1024, H=16, DH=64. f32 in / f32 out, bf16 MFMA internally.

typedef unsigned short u16;
typedef unsigned int u32;
typedef __bf16 bf16x8 __attribute__((ext_vector_type(8)));
typedef float  f32x4  __attribute__((ext_vector_type(4)));
typedef unsigned short u16x4 __attribute__((ext_vector_type(4)));

#define DEV __device__ __forceinline__

DEV float exp2fast(float x) { return __builtin_amdgcn_exp2f(x); }  // v_exp_f32

DEV u16 f2bf(float f) {
  unsigned u = __builtin_bit_cast(unsigned, f);
  return (u16)((u + 0x7FFFu + ((u >> 16) & 1u)) >> 16);  // RNE
}

DEV f32x4 mfma16(bf16x8 a, bf16x8 b, f32x4 c) {
  return __builtin_amdgcn_mfma_f32_16x16x32_bf16(a, b, c, 0, 0, 0);
}

template <typename T>
DEV void gload16(const T* g, T* l) {  // global -> LDS, 16B per lane, dest = base + lane*16
  __builtin_amdgcn_global_load_lds((__attribute__((address_space(1))) void*)g,
                                   (__attribute__((address_space(3))) void*)l, 16, 0, 0);
}

// ---------------- prep kernels ----------------

__global__ __launch_bounds__(256) void cvt_x(const float* __restrict__ x,
                                             u16* __restrict__ xb) {
  int idx = (blockIdx.x * 256 + threadIdx.x) * 4;
  float4 v = *(const float4*)(x + idx);
  u16x4 u = { f2bf(v.x), f2bf(v.y), f2bf(v.z), f2bf(v.w) };
  *(u16x4*)(xb + idx) = u;
}

// dst[c][r] = bf16(src[r][c] * (c < scaleLim ? qscale : 1));  src [R][C], dst [C][R]
__global__ __launch_bounds__(256) void wtrans(const float* __restrict__ src,
                                              u16* __restrict__ dst,
                                              int R, int C, int scaleLim) {
  __shared__ u16 T[64][72];
  const int tid = threadIdx.x;
  const int c0 = blockIdx.x * 64, r0 = blockIdx.y * 64;
  const int cl = tid & 63;
  // q-scale folded: 1/sqrt(64) * log2(e)  (softmax runs in exp2 domain)
  const float scale = (c0 + cl < scaleLim) ? 0.125f * 1.4426950408889634f : 1.0f;
#pragma unroll
  for (int i = 0; i < 16; ++i) {
    int r = (tid >> 6) * 16 + i;
    T[cl][r] = f2bf(src[(size_t)(r0 + r) * C + c0 + cl] * scale);
  }
  __syncthreads();
#pragma unroll
  for (int i = 0; i < 16; ++i) {
    int cc = (tid >> 6) * 16 + i;
    dst[(size_t)(c0 + cc) * R + r0 + cl] = T[cc][cl];
  }
}

// V part of qkv -> vt[b][h][d][n]   (kv-contiguous for the PV B-operand)
__global__ __launch_bounds__(256) void vtrans(const u16* __restrict__ qkv,
                                              u16* __restrict__ vtout) {
  __shared__ u16 T[64][72];
  const int tid = threadIdx.x;
  const int n0 = blockIdx.x * 64;
  const int h = blockIdx.y, b = blockIdx.z;
  const int dl = tid & 63;
#pragma unroll
  for (int i = 0; i < 16; ++i) {
    int n = (tid >> 6) * 16 + i;
    T[dl][n] = qkv[(size_t)(b * 2048 + n0 + n) * 3072 + 2048 + h * 64 + dl];
  }
  __syncthreads();
#pragma unroll
  for (int i = 0; i < 16; ++i) {
    int d = (tid >> 6) * 16 + i;
    vtout[(size_t)((b * 16 + h) * 64 + d) * 2048 + n0 + dl] = T[d][dl];
  }
}

// ---------------- GEMM: C[M,N] = A[M,1024] * Bt[N,1024]^T ----------------

__global__ __launch_bounds__(256) void gemm_bf16(const u16* __restrict__ A,
                                                 const u16* __restrict__ Bt,
                                                 u16* __restrict__ Cb,
                                                 float* __restrict__ Cf, int N) {
  __shared__ __align__(16) u16 lA[128 * 64];
  __shared__ __align__(16) u16 lB[128 * 64];
  const int tid = threadIdx.x;
  const int lane = tid & 63, w = tid >> 6;
  const int g = lane >> 4, r16 = lane & 15;
  const int wm = w >> 1, wn = w & 1;
  const int m0 = blockIdx.y * 128, n0 = blockIdx.x * 128;

  const f32x4 z4 = {0.f, 0.f, 0.f, 0.f};
  f32x4 acc[4][4];
#pragma unroll
  for (int m = 0; m < 4; ++m)
#pragma unroll
    for (int n = 0; n < 4; ++n) acc[m][n] = z4;

  for (int kt = 0; kt < 16; ++kt) {
    const int kbase = kt * 64;
#pragma unroll
    for (int issue = 0; issue < 4; ++issue) {
      int i = issue * 256 + tid;
      int r = i >> 3, jp = (i & 7) ^ (r & 7);  // swizzled source chunk
      gload16(A + (size_t)(m0 + r) * 1024 + kbase + jp * 8,
              lA + (size_t)(issue * 256 + (tid & ~63)) * 8);
      gload16(Bt + (size_t)(n0 + r) * 1024 + kbase + jp * 8,
              lB + (size_t)(issue * 256 + (tid & ~63)) * 8);
    }
    __syncthreads();
#pragma unroll
    for (int kk = 0; kk < 2; ++kk) {
      bf16x8 a[4], b[4];
#pragma unroll
      for (int m = 0; m < 4; ++m) {
        int row = wm * 64 + m * 16 + r16;
        int off = row * 128 + ((kk * 64 + g * 16) ^ ((r16 & 7) << 4));
        a[m] = *(const bf16x8*)((const char*)lA + off);
      }
#pragma unroll
      for (int n = 0; n < 4; ++n) {
        int row = wn * 64 + n * 16 + r16;
        int off = row * 128 + ((kk * 64 + g * 16) ^ ((r16 & 7) << 4));
        b[n] = *(const bf16x8*)((const char*)lB + off);
      }
#pragma unroll
      for (int m = 0; m < 4; ++m)
#pragma unroll
        for (int n = 0; n < 4; ++n) acc[m][n] = mfma16(a[m], b[n], acc[m][n]);
    }
    __syncthreads();
  }
#pragma unroll
  for (int m = 0; m < 4; ++m)
#pragma unroll
    for (int n = 0; n < 4; ++n) {
      int col = n0 + wn * 64 + n * 16 + r16;
#pragma unroll
      for (int j = 0; j < 4; ++j) {
        int row = m0 + wm * 64 + m * 16 + g * 4 + j;
        if (Cb) Cb[(size_t)row * N + col] = f2bf(acc[m][n][j]);
        else    Cf[(size_t)row * N + col] = acc[m][n][j];
      }
    }
}

// ---------------- fused causal flash attention (swapped QK^T) ----------------
// QBLK=64 (4 waves x 16 q-rows), KVBLK=64, grid 1024 (4 blocks/CU, all resident).
// S^T = mfma(K, Q): lane owns ONE q-row (q = r16) -> in-lane softmax, scalar
// m/l state, 2 shfl_xor per reduce. P packed to per-wave LDS as u32 pairs;
// PV reads it back as the A-operand. exp2-domain softmax (log2e folded into Q).
// 256 threads stage half a 64x64 tile per gload -> second gload advances the
// SOURCE by 32 rows (32*stride), dest by 2048 elements.

__global__ __launch_bounds__(256) void attn_fused(const u16* __restrict__ qkv,
                                                  const u16* __restrict__ vt,
                                                  u16* __restrict__ ao) {
  __shared__ __align__(16) u16 lK[2][64 * 64];
  __shared__ __align__(16) u16 lV[2][64 * 64];
  __shared__ __align__(16) u16 lP[4][16 * 64];
  const int tid = threadIdx.x;
  const int lane = tid & 63, w = tid >> 6;
  const int g = lane >> 4, r16 = lane & 15;

  // decode XCD-swizzled flat id; qt paired heavy/light for CU balance
  const int flat = (int)blockIdx.x;
  const int xcd = flat & 7, slot = flat >> 3;     // slot 0..127
  const int grp = xcd * 4 + (slot >> 5);          // b*16+h
  const int s5 = slot & 31;
  const int qt = (s5 & 1) ? (s5 >> 1) : (31 - (s5 >> 1));  // 31,0,30,1,...
  const int b = grp >> 4, h = grp & 15;
  const int q0w = qt * 64 + w * 16;

  // Q fragments in registers (q-row = r16), scale*log2e folded into wqkvT
  bf16x8 aq[2];
  {
    const u16* qrow = qkv + (size_t)(b * 2048 + q0w + r16) * 3072 + h * 64;
    aq[0] = *(const bf16x8*)(qrow + g * 8);
    aq[1] = *(const bf16x8*)(qrow + 32 + g * 8);
  }

  const int r = tid >> 3, jp = (tid & 7) ^ (r & 7);  // staging decomposition
  const u16* ksrc = qkv + (size_t)(b * 2048 + r) * 3072 + 1024 + h * 64 + jp * 8;
  const u16* vsrc = vt + (size_t)((b * 16 + h) * 64 + r) * 2048 + jp * 8;
  const size_t ldst = (size_t)(tid & ~63) * 8;

  const f32x4 z4 = {0.f, 0.f, 0.f, 0.f};
  f32x4 o[4];
#pragma unroll
  for (int n = 0; n < 4; ++n) o[n] = z4;
  float mrun = -INFINITY, lrun = 0.f;

  const int nt = qt + 1;
  gload16(ksrc, lK[0] + ldst);
  gload16(ksrc + (size_t)32 * 3072, lK[0] + 2048 + ldst);   // rows 32..63
  gload16(vsrc, lV[0] + ldst);
  gload16(vsrc + (size_t)32 * 2048, lV[0] + 2048 + ldst);   // rows 32..63
  __syncthreads();

  int cur = 0;
  u16* lp = lP[w];
  for (int t = 0; t < nt; ++t) {
    if (t + 1 < nt) {  // prefetch next K/V tile into the other buffer
      const u16* kn = ksrc + (size_t)(t + 1) * 64 * 3072;
      const u16* vn = vsrc + (size_t)(t + 1) * 64;
      gload16(kn, lK[cur ^ 1] + ldst);
      gload16(kn + (size_t)32 * 3072, lK[cur ^ 1] + 2048 + ldst);
      gload16(vn, lV[cur ^ 1] + ldst);
      gload16(vn + (size_t)32 * 2048, lV[cur ^ 1] + 2048 + ldst);
    }
    // S^T = K Q^T : s[f][j] -> q = r16, kv = f*16 + g*4 + j
    f32x4 s[4];
#pragma unroll
    for (int f = 0; f < 4; ++f) s[f] = z4;
#pragma unroll
    for (int kk = 0; kk < 2; ++kk) {
#pragma unroll
      for (int f = 0; f < 4; ++f) {
        int row = f * 16 + r16;
        int off = row * 128 + ((kk * 64 + g * 16) ^ ((r16 & 7) << 4));
        bf16x8 ak = *(const bf16x8*)((const char*)lK[cur] + off);
        s[f] = mfma16(ak, aq[kk], s[f]);  // A = K rows, B = Q rows
      }
    }
    if (t == qt) {  // diagonal tile: causal mask (kv > q)
      const int qrel = w * 16 + r16;  // q - kv0
#pragma unroll
      for (int f = 0; f < 4; ++f)
#pragma unroll
        for (int j = 0; j < 4; ++j)
          if (f * 16 + g * 4 + j > qrel) s[f][j] = -3.0e38f;
    }
    // in-lane online softmax (exp2 domain), lane owns q-row r16
    float mx = fmaxf(fmaxf(fmaxf(s[0][0], s[0][1]), fmaxf(s[0][2], s[0][3])),
                     fmaxf(fmaxf(s[1][0], s[1][1]), fmaxf(s[1][2], s[1][3])));
    mx = fmaxf(mx, fmaxf(fmaxf(fmaxf(s[2][0], s[2][1]), fmaxf(s[2][2], s[2][3])),
                         fmaxf(fmaxf(s[3][0], s[3][1]), fmaxf(s[3][2], s[3][3]))));
    mx = fmaxf(mx, __shfl_xor(mx, 16));
    mx = fmaxf(mx, __shfl_xor(mx, 32));
    float mnew = fmaxf(mrun, mx);
    float corr = exp2fast(mrun - mnew);
    mrun = mnew;
    float sm = 0.f;
#pragma unroll
    for (int f = 0; f < 4; ++f)
#pragma unroll
      for (int j = 0; j < 4; ++j) {
        s[f][j] = exp2fast(s[f][j] - mnew);
        sm += s[f][j];
      }
    sm += __shfl_xor(sm, 16);
    sm += __shfl_xor(sm, 32);
    lrun = lrun * corr + sm;
    // redistribute corr to the O layout (o rows = q = g*4+j)
    float cj[4];
#pragma unroll
    for (int j = 0; j < 4; ++j) cj[j] = __shfl(corr, g * 4 + j);
#pragma unroll
    for (int n = 0; n < 4; ++n)
#pragma unroll
      for (int j = 0; j < 4; ++j) o[n][j] *= cj[j];

    // P -> per-wave LDS, packed u32 (kv pairs), swizzled rows
#pragma unroll
    for (int f = 0; f < 4; ++f) {
      u32 w0 = (u32)f2bf(s[f][0]) | ((u32)f2bf(s[f][1]) << 16);
      u32 w1 = (u32)f2bf(s[f][2]) | ((u32)f2bf(s[f][3]) << 16);
      int base = r16 * 128 + ((f * 32 + g * 8) ^ ((r16 & 7) << 4));
      *(u32*)((char*)lp + base) = w0;
      *(u32*)((char*)lp + base + 4) = w1;
    }
    // PV: A = P rows (q = r16), B = V^T rows (d)
#pragma unroll
    for (int ks = 0; ks < 2; ++ks) {
      int abyte = r16 * 128 + ((ks * 64 + g * 16) ^ ((r16 & 7) << 4));
      bf16x8 ap = *(const bf16x8*)((const char*)lp + abyte);
#pragma unroll
      for (int n = 0; n < 4; ++n) {
        int row = n * 16 + r16;
        int off = row * 128 + ((ks * 64 + g * 16) ^ ((r16 & 7) << 4));
        bf16x8 bv = *(const bf16x8*)((const char*)lV[cur] + off);
        o[n] = mfma16(ap, bv, o[n]);
      }
    }
    __syncthreads();  // drains prefetch + protects buffer swap
    cur ^= 1;
  }
  // epilogue: O rows = q = g*4+j, cols = d = n*16+r16
  float lj[4];
#pragma unroll
  for (int j = 0; j < 4; ++j) lj[j] = __shfl(lrun, g * 4 + j);
#pragma unroll
  for (int n = 0; n < 4; ++n) {
    int col = h * 64 + n * 16 + r16;
#pragma unroll
    for (int j = 0; j < 4; ++j) {
      int row = b * 2048 + q0w + g * 4 + j;
      ao[(size_t)row * 1024 + col] = f2bf(o[n][j] * (1.f / lj[j]));
    }
  }
}

// ---------------- launch ----------------

extern "C" void kernel_launch(void* const* d_in, const int* in_sizes, int n_in,
                              void* d_out, int out_size, void* d_ws, size_t ws_size,
                              hipStream_t stream) {
  const float* x     = (const float*)d_in[0];
  // d_in[1] = attn_mask: causal tril, implemented analytically — unused.
  const float* w_qkv = (const float*)d_in[2];
  const float* w_out = (const float*)d_in[3];
  float* out = (float*)d_out;

  u16* ws = (u16*)d_ws;
  u16* x_bf  = ws;                               // 4096*1024           (4M)
  u16* wqkvT = x_bf + (size_t)4096 * 1024;       // 3072*1024           (3M)
  u16* woutT = wqkvT + (size_t)3072 * 1024;      // 1024*1024           (1M)
  u16* qkv   = woutT + (size_t)1024 * 1024;      // 4096*3072           (12M)
  u16* ao    = qkv + (size_t)4096 * 3072;        // 4096*1024           (4M)
  u16* vtb   = x_bf;                             // 2048*2048, aliases x_bf (dead after GEMM1)

  cvt_x<<<4096, 256, 0, stream>>>(x, x_bf);
  wtrans<<<dim3(48, 16), 256, 0, stream>>>(w_qkv, wqkvT, 1024, 3072, 1024);  // fold q-scale*log2e
  wtrans<<<dim3(16, 16), 256, 0, stream>>>(w_out, woutT, 1024, 1024, 0);
  gemm_bf16<<<dim3(24, 32), 256, 0, stream>>>(x_bf, wqkvT, qkv, nullptr, 3072);
  vtrans<<<dim3(32, 16, 2), 256, 0, stream>>>(qkv, vtb);
  attn_fused<<<1024, 256, 0, stream>>>(qkv, vtb, ao);
  gemm_bf16<<<dim3(8, 32), 256, 0, stream>>>(ao, woutT, nullptr, out, 1024);
}

// Round 6
// 216.816 us; speedup vs baseline: 1.3106x; 1.1227x over previous
//
#include <hip/hip_runtime.h>
#include <hip/hip_bf16.h>

// B=2, N=2048, D=1024, H=16, DH=64. f32 in / f32 out, bf16 MFMA internally.

typedef unsigned short u16;
typedef unsigned int u32;
typedef __bf16 bf16x8 __attribute__((ext_vector_type(8)));
typedef float  f32x4  __attribute__((ext_vector_type(4)));
typedef unsigned short u16x4 __attribute__((ext_vector_type(4)));

#define DEV __device__ __forceinline__

DEV float exp2fast(float x) { return __builtin_amdgcn_exp2f(x); }  // v_exp_f32

DEV u16 f2bf(float f) {
  unsigned u = __builtin_bit_cast(unsigned, f);
  return (u16)((u + 0x7FFFu + ((u >> 16) & 1u)) >> 16);  // RNE
}

DEV f32x4 mfma16(bf16x8 a, bf16x8 b, f32x4 c) {
  return __builtin_amdgcn_mfma_f32_16x16x32_bf16(a, b, c, 0, 0, 0);
}

template <typename T>
DEV void gload16(const T* g, T* l) {  // global -> LDS, 16B per lane, dest = base + lane*16
  __builtin_amdgcn_global_load_lds((__attribute__((address_space(1))) void*)g,
                                   (__attribute__((address_space(3))) void*)l, 16, 0, 0);
}

// ---------------- prep kernels ----------------

__global__ __launch_bounds__(256) void cvt_x(const float* __restrict__ x,
                                             u16* __restrict__ xb) {
  int idx = (blockIdx.x * 256 + threadIdx.x) * 4;
  float4 v = *(const float4*)(x + idx);
  u16x4 u = { f2bf(v.x), f2bf(v.y), f2bf(v.z), f2bf(v.w) };
  *(u16x4*)(xb + idx) = u;
}

// dst[c][r] = bf16(src[r][c] * (c < scaleLim ? qscale : 1));  src [R][C], dst [C][R]
__global__ __launch_bounds__(256) void wtrans(const float* __restrict__ src,
                                              u16* __restrict__ dst,
                                              int R, int C, int scaleLim) {
  __shared__ u16 T[64][72];
  const int tid = threadIdx.x;
  const int c0 = blockIdx.x * 64, r0 = blockIdx.y * 64;
  const int cl = tid & 63;
  // q-scale folded: 1/sqrt(64) * log2(e)  (softmax runs in exp2 domain)
  const float scale = (c0 + cl < scaleLim) ? 0.125f * 1.4426950408889634f : 1.0f;
#pragma unroll
  for (int i = 0; i < 16; ++i) {
    int r = (tid >> 6) * 16 + i;
    T[cl][r] = f2bf(src[(size_t)(r0 + r) * C + c0 + cl] * scale);
  }
  __syncthreads();
#pragma unroll
  for (int i = 0; i < 16; ++i) {
    int cc = (tid >> 6) * 16 + i;
    dst[(size_t)(c0 + cc) * R + r0 + cl] = T[cc][cl];
  }
}

// V part of qkv -> vt[b][h][d][n]   (kv-contiguous for the PV B-operand)
__global__ __launch_bounds__(256) void vtrans(const u16* __restrict__ qkv,
                                              u16* __restrict__ vtout) {
  __shared__ u16 T[64][72];
  const int tid = threadIdx.x;
  const int n0 = blockIdx.x * 64;
  const int h = blockIdx.y, b = blockIdx.z;
  const int dl = tid & 63;
#pragma unroll
  for (int i = 0; i < 16; ++i) {
    int n = (tid >> 6) * 16 + i;
    T[dl][n] = qkv[(size_t)(b * 2048 + n0 + n) * 3072 + 2048 + h * 64 + dl];
  }
  __syncthreads();
#pragma unroll
  for (int i = 0; i < 16; ++i) {
    int d = (tid >> 6) * 16 + i;
    vtout[(size_t)((b * 16 + h) * 64 + d) * 2048 + n0 + dl] = T[d][dl];
  }
}

// ---------------- GEMM: C[M,N] = A[M,1024] * Bt[N,1024]^T ----------------
// 1D grid, bijective XCD swizzle (m204): newid = (id&7)*(nwg/8) + (id>>3).

__global__ __launch_bounds__(256) void gemm_bf16(const u16* __restrict__ A,
                                                 const u16* __restrict__ Bt,
                                                 u16* __restrict__ Cb,
                                                 float* __restrict__ Cf,
                                                 int N, int nx, int cpx) {
  __shared__ __align__(16) u16 lA[128 * 64];
  __shared__ __align__(16) u16 lB[128 * 64];
  const int tid = threadIdx.x;
  const int lane = tid & 63, w = tid >> 6;
  const int g = lane >> 4, r16 = lane & 15;
  const int wm = w >> 1, wn = w & 1;
  const int id = (int)blockIdx.x;
  const int newid = (id & 7) * cpx + (id >> 3);  // nwg % 8 == 0 in all our launches
  const int m0 = (newid / nx) * 128, n0 = (newid % nx) * 128;

  const f32x4 z4 = {0.f, 0.f, 0.f, 0.f};
  f32x4 acc[4][4];
#pragma unroll
  for (int m = 0; m < 4; ++m)
#pragma unroll
    for (int n = 0; n < 4; ++n) acc[m][n] = z4;

  for (int kt = 0; kt < 16; ++kt) {
    const int kbase = kt * 64;
#pragma unroll
    for (int issue = 0; issue < 4; ++issue) {
      int i = issue * 256 + tid;
      int r = i >> 3, jp = (i & 7) ^ (r & 7);  // swizzled source chunk
      gload16(A + (size_t)(m0 + r) * 1024 + kbase + jp * 8,
              lA + (size_t)(issue * 256 + (tid & ~63)) * 8);
      gload16(Bt + (size_t)(n0 + r) * 1024 + kbase + jp * 8,
              lB + (size_t)(issue * 256 + (tid & ~63)) * 8);
    }
    __syncthreads();
#pragma unroll
    for (int kk = 0; kk < 2; ++kk) {
      bf16x8 a[4], b[4];
#pragma unroll
      for (int m = 0; m < 4; ++m) {
        int row = wm * 64 + m * 16 + r16;
        int off = row * 128 + ((kk * 64 + g * 16) ^ ((r16 & 7) << 4));
        a[m] = *(const bf16x8*)((const char*)lA + off);
      }
#pragma unroll
      for (int n = 0; n < 4; ++n) {
        int row = wn * 64 + n * 16 + r16;
        int off = row * 128 + ((kk * 64 + g * 16) ^ ((r16 & 7) << 4));
        b[n] = *(const bf16x8*)((const char*)lB + off);
      }
      __builtin_amdgcn_s_setprio(1);
#pragma unroll
      for (int m = 0; m < 4; ++m)
#pragma unroll
        for (int n = 0; n < 4; ++n) acc[m][n] = mfma16(a[m], b[n], acc[m][n]);
      __builtin_amdgcn_s_setprio(0);
    }
    __syncthreads();
  }
#pragma unroll
  for (int m = 0; m < 4; ++m)
#pragma unroll
    for (int n = 0; n < 4; ++n) {
      int col = n0 + wn * 64 + n * 16 + r16;
#pragma unroll
      for (int j = 0; j < 4; ++j) {
        int row = m0 + wm * 64 + m * 16 + g * 4 + j;
        if (Cb) Cb[(size_t)row * N + col] = f2bf(acc[m][n][j]);
        else    Cf[(size_t)row * N + col] = acc[m][n][j];
      }
    }
}

// ---------------- fused causal flash attention (swapped QK^T) ----------------
// Balance BY CONSTRUCTION: each block does a PAIR of q-tiles (qtA=31-p heavy,
// qtB=p light) sequentially -> exactly 33 tile-steps per block, no tail.
// Grid 512 (2 blocks/CU). QBLK=64 (4 waves x 16 q-rows), KVBLK=64, dbuf K/V
// with one-tile prefetch. S^T = mfma(K,Q): lane owns one q-row -> in-lane
// softmax (exp2 domain), scalar m/l, 2 shfl_xor per reduce.

__global__ __launch_bounds__(256) void attn_fused(const u16* __restrict__ qkv,
                                                  const u16* __restrict__ vt,
                                                  u16* __restrict__ ao) {
  __shared__ __align__(16) u16 lK[2][64 * 64];
  __shared__ __align__(16) u16 lV[2][64 * 64];
  __shared__ __align__(16) u16 lP[4][16 * 64];
  const int tid = threadIdx.x;
  const int lane = tid & 63, w = tid >> 6;
  const int g = lane >> 4, r16 = lane & 15;

  // flat in [0,512): xcd-swizzled; pair p in [0,16)
  const int flat = (int)blockIdx.x;
  const int xcd = flat & 7, slot = flat >> 3;     // slot 0..63
  const int grp = xcd * 4 + (slot >> 4);          // b*16+h
  const int pair = slot & 15;
  const int b = grp >> 4, h = grp & 15;

  const int r = tid >> 3, jp = (tid & 7) ^ (r & 7);  // staging decomposition
  const u16* ksrc = qkv + (size_t)(b * 2048 + r) * 3072 + 1024 + h * 64 + jp * 8;
  const u16* vsrc = vt + (size_t)((b * 16 + h) * 64 + r) * 2048 + jp * 8;
  const size_t ldst = (size_t)(tid & ~63) * 8;

  const f32x4 z4 = {0.f, 0.f, 0.f, 0.f};
  u16* lp = lP[w];
  int cur = 0;

#pragma unroll 1
  for (int ph = 0; ph < 2; ++ph) {
    const int qt = ph ? pair : 31 - pair;  // heavy first
    const int q0w = qt * 64 + w * 16;

    // Q fragments (q-row = r16), scale*log2e folded into wqkvT
    bf16x8 aq[2];
    {
      const u16* qrow = qkv + (size_t)(b * 2048 + q0w + r16) * 3072 + h * 64;
      aq[0] = *(const bf16x8*)(qrow + g * 8);
      aq[1] = *(const bf16x8*)(qrow + 32 + g * 8);
    }
    f32x4 o[4];
#pragma unroll
    for (int n = 0; n < 4; ++n) o[n] = z4;
    float mrun = -INFINITY, lrun = 0.f;

    // stage tile 0 of this phase
    gload16(ksrc, lK[cur] + ldst);
    gload16(ksrc + (size_t)32 * 3072, lK[cur] + 2048 + ldst);
    gload16(vsrc, lV[cur] + ldst);
    gload16(vsrc + (size_t)32 * 2048, lV[cur] + 2048 + ldst);
    __syncthreads();

    for (int t = 0; t <= qt; ++t) {
      if (t < qt) {  // prefetch next K/V tile into the other buffer
        const u16* kn = ksrc + (size_t)(t + 1) * 64 * 3072;
        const u16* vn = vsrc + (size_t)(t + 1) * 64;
        gload16(kn, lK[cur ^ 1] + ldst);
        gload16(kn + (size_t)32 * 3072, lK[cur ^ 1] + 2048 + ldst);
        gload16(vn, lV[cur ^ 1] + ldst);
        gload16(vn + (size_t)32 * 2048, lV[cur ^ 1] + 2048 + ldst);
      }
      // S^T = K Q^T : s[f][j] -> q = r16, kv = f*16 + g*4 + j
      f32x4 s[4];
#pragma unroll
      for (int f = 0; f < 4; ++f) s[f] = z4;
      __builtin_amdgcn_s_setprio(1);
#pragma unroll
      for (int kk = 0; kk < 2; ++kk) {
#pragma unroll
        for (int f = 0; f < 4; ++f) {
          int row = f * 16 + r16;
          int off = row * 128 + ((kk * 64 + g * 16) ^ ((r16 & 7) << 4));
          bf16x8 ak = *(const bf16x8*)((const char*)lK[cur] + off);
          s[f] = mfma16(ak, aq[kk], s[f]);  // A = K rows, B = Q rows
        }
      }
      __builtin_amdgcn_s_setprio(0);
      if (t == qt) {  // diagonal tile: causal mask (kv > q)
        const int qrel = w * 16 + r16;  // q - kv0
#pragma unroll
        for (int f = 0; f < 4; ++f)
#pragma unroll
          for (int j = 0; j < 4; ++j)
            if (f * 16 + g * 4 + j > qrel) s[f][j] = -3.0e38f;
      }
      // in-lane online softmax (exp2 domain), lane owns q-row r16
      float mx = fmaxf(fmaxf(fmaxf(s[0][0], s[0][1]), fmaxf(s[0][2], s[0][3])),
                       fmaxf(fmaxf(s[1][0], s[1][1]), fmaxf(s[1][2], s[1][3])));
      mx = fmaxf(mx, fmaxf(fmaxf(fmaxf(s[2][0], s[2][1]), fmaxf(s[2][2], s[2][3])),
                           fmaxf(fmaxf(s[3][0], s[3][1]), fmaxf(s[3][2], s[3][3]))));
      mx = fmaxf(mx, __shfl_xor(mx, 16));
      mx = fmaxf(mx, __shfl_xor(mx, 32));
      float mnew = fmaxf(mrun, mx);
      float corr = exp2fast(mrun - mnew);
      mrun = mnew;
      float sm = 0.f;
#pragma unroll
      for (int f = 0; f < 4; ++f)
#pragma unroll
        for (int j = 0; j < 4; ++j) {
          s[f][j] = exp2fast(s[f][j] - mnew);
          sm += s[f][j];
        }
      sm += __shfl_xor(sm, 16);
      sm += __shfl_xor(sm, 32);
      lrun = lrun * corr + sm;
      // redistribute corr to the O layout (o rows = q = g*4+j)
      float cj[4];
#pragma unroll
      for (int j = 0; j < 4; ++j) cj[j] = __shfl(corr, g * 4 + j);
#pragma unroll
      for (int n = 0; n < 4; ++n)
#pragma unroll
        for (int j = 0; j < 4; ++j) o[n][j] *= cj[j];

      // P -> per-wave LDS, packed u32 (kv pairs), swizzled rows
#pragma unroll
      for (int f = 0; f < 4; ++f) {
        u32 w0 = (u32)f2bf(s[f][0]) | ((u32)f2bf(s[f][1]) << 16);
        u32 w1 = (u32)f2bf(s[f][2]) | ((u32)f2bf(s[f][3]) << 16);
        int base = r16 * 128 + ((f * 32 + g * 8) ^ ((r16 & 7) << 4));
        *(u32*)((char*)lp + base) = w0;
        *(u32*)((char*)lp + base + 4) = w1;
      }
      // PV: A = P rows (q = r16), B = V^T rows (d)
      __builtin_amdgcn_s_setprio(1);
#pragma unroll
      for (int ks = 0; ks < 2; ++ks) {
        int abyte = r16 * 128 + ((ks * 64 + g * 16) ^ ((r16 & 7) << 4));
        bf16x8 ap = *(const bf16x8*)((const char*)lp + abyte);
#pragma unroll
        for (int n = 0; n < 4; ++n) {
          int row = n * 16 + r16;
          int off = row * 128 + ((ks * 64 + g * 16) ^ ((r16 & 7) << 4));
          bf16x8 bv = *(const bf16x8*)((const char*)lV[cur] + off);
          o[n] = mfma16(ap, bv, o[n]);
        }
      }
      __builtin_amdgcn_s_setprio(0);
      __syncthreads();  // drains prefetch + protects buffer swap
      cur ^= 1;
    }
    // epilogue: O rows = q = g*4+j, cols = d = n*16+r16
    float lj[4];
#pragma unroll
    for (int j = 0; j < 4; ++j) lj[j] = __shfl(lrun, g * 4 + j);
#pragma unroll
    for (int n = 0; n < 4; ++n) {
      int col = h * 64 + n * 16 + r16;
#pragma unroll
      for (int j = 0; j < 4; ++j) {
        int row = b * 2048 + q0w + g * 4 + j;
        ao[(size_t)row * 1024 + col] = f2bf(o[n][j] * (1.f / lj[j]));
      }
    }
  }
}

// ---------------- launch ----------------

extern "C" void kernel_launch(void* const* d_in, const int* in_sizes, int n_in,
                              void* d_out, int out_size, void* d_ws, size_t ws_size,
                              hipStream_t stream) {
  const float* x     = (const float*)d_in[0];
  // d_in[1] = attn_mask: causal tril, implemented analytically — unused.
  const float* w_qkv = (const float*)d_in[2];
  const float* w_out = (const float*)d_in[3];
  float* out = (float*)d_out;

  u16* ws = (u16*)d_ws;
  u16* x_bf  = ws;                               // 4096*1024           (4M)
  u16* wqkvT = x_bf + (size_t)4096 * 1024;       // 3072*1024           (3M)
  u16* woutT = wqkvT + (size_t)3072 * 1024;      // 1024*1024           (1M)
  u16* qkv   = woutT + (size_t)1024 * 1024;      // 4096*3072           (12M)
  u16* ao    = qkv + (size_t)4096 * 3072;        // 4096*1024           (4M)
  u16* vtb   = x_bf;                             // 2048*2048, aliases x_bf (dead after GEMM1)

  cvt_x<<<4096, 256, 0, stream>>>(x, x_bf);
  wtrans<<<dim3(48, 16), 256, 0, stream>>>(w_qkv, wqkvT, 1024, 3072, 1024);  // fold q-scale*log2e
  wtrans<<<dim3(16, 16), 256, 0, stream>>>(w_out, woutT, 1024, 1024, 0);
  gemm_bf16<<<768, 256, 0, stream>>>(x_bf, wqkvT, qkv, nullptr, 3072, 24, 96);
  vtrans<<<dim3(32, 16, 2), 256, 0, stream>>>(qkv, vtb);
  attn_fused<<<512, 256, 0, stream>>>(qkv, vtb, ao);
  gemm_bf16<<<256, 256, 0, stream>>>(ao, woutT, nullptr, out, 1024, 8, 32);
}

// Round 7
// 195.192 us; speedup vs baseline: 1.4557x; 1.1108x over previous
//
#include <hip/hip_runtime.h>
#include <hip/hip_bf16.h>

// B=2, N=2048, D=1024, H=16, DH=64. f32 in / f32 out, bf16 MFMA internally.

typedef unsigned short u16;
typedef unsigned int u32;
typedef __bf16 bf16x8 __attribute__((ext_vector_type(8)));
typedef float  f32x4  __attribute__((ext_vector_type(4)));
typedef unsigned short u16x4 __attribute__((ext_vector_type(4)));

#define DEV __device__ __forceinline__

DEV float exp2fast(float x) { return __builtin_amdgcn_exp2f(x); }  // v_exp_f32

DEV u16 f2bf(float f) {
  unsigned u = __builtin_bit_cast(unsigned, f);
  return (u16)((u + 0x7FFFu + ((u >> 16) & 1u)) >> 16);  // RNE
}

DEV f32x4 mfma16(bf16x8 a, bf16x8 b, f32x4 c) {
  return __builtin_amdgcn_mfma_f32_16x16x32_bf16(a, b, c, 0, 0, 0);
}

template <typename T>
DEV void gload16(const T* g, T* l) {  // global -> LDS, 16B per lane, dest = base + lane*16
  __builtin_amdgcn_global_load_lds((__attribute__((address_space(1))) void*)g,
                                   (__attribute__((address_space(3))) void*)l, 16, 0, 0);
}

// ---------------- prep kernels ----------------

__global__ __launch_bounds__(256) void cvt_x(const float* __restrict__ x,
                                             u16* __restrict__ xb) {
  int idx = (blockIdx.x * 256 + threadIdx.x) * 4;
  float4 v = *(const float4*)(x + idx);
  u16x4 u = { f2bf(v.x), f2bf(v.y), f2bf(v.z), f2bf(v.w) };
  *(u16x4*)(xb + idx) = u;
}

// dst[c][r] = bf16(src[r][c] * (c < scaleLim ? qscale : 1));  src [R][C], dst [C][R]
__global__ __launch_bounds__(256) void wtrans(const float* __restrict__ src,
                                              u16* __restrict__ dst,
                                              int R, int C, int scaleLim) {
  __shared__ u16 T[64][72];
  const int tid = threadIdx.x;
  const int c0 = blockIdx.x * 64, r0 = blockIdx.y * 64;
  const int cl = tid & 63;
  // q-scale folded: 1/sqrt(64) * log2(e)  (softmax runs in exp2 domain)
  const float scale = (c0 + cl < scaleLim) ? 0.125f * 1.4426950408889634f : 1.0f;
#pragma unroll
  for (int i = 0; i < 16; ++i) {
    int r = (tid >> 6) * 16 + i;
    T[cl][r] = f2bf(src[(size_t)(r0 + r) * C + c0 + cl] * scale);
  }
  __syncthreads();
#pragma unroll
  for (int i = 0; i < 16; ++i) {
    int cc = (tid >> 6) * 16 + i;
    dst[(size_t)(c0 + cc) * R + r0 + cl] = T[cc][cl];
  }
}

// V part of qkv -> vt[b][h][d][n]   (kv-contiguous for the PV B-operand)
__global__ __launch_bounds__(256) void vtrans(const u16* __restrict__ qkv,
                                              u16* __restrict__ vtout) {
  __shared__ u16 T[64][72];
  const int tid = threadIdx.x;
  const int n0 = blockIdx.x * 64;
  const int h = blockIdx.y, b = blockIdx.z;
  const int dl = tid & 63;
#pragma unroll
  for (int i = 0; i < 16; ++i) {
    int n = (tid >> 6) * 16 + i;
    T[dl][n] = qkv[(size_t)(b * 2048 + n0 + n) * 3072 + 2048 + h * 64 + dl];
  }
  __syncthreads();
#pragma unroll
  for (int i = 0; i < 16; ++i) {
    int d = (tid >> 6) * 16 + i;
    vtout[(size_t)((b * 16 + h) * 64 + d) * 2048 + n0 + dl] = T[d][dl];
  }
}

// ---------------- GEMM1: C[M,N] = A[M,1024] * Bt[N,1024]^T, 128x128 tile ----
// 1D grid, bijective XCD swizzle (m204): newid = (id&7)*(nwg/8) + (id>>3).

__global__ __launch_bounds__(256) void gemm_bf16(const u16* __restrict__ A,
                                                 const u16* __restrict__ Bt,
                                                 u16* __restrict__ Cb,
                                                 int N, int nx, int cpx) {
  __shared__ __align__(16) u16 lA[128 * 64];
  __shared__ __align__(16) u16 lB[128 * 64];
  const int tid = threadIdx.x;
  const int lane = tid & 63, w = tid >> 6;
  const int g = lane >> 4, r16 = lane & 15;
  const int wm = w >> 1, wn = w & 1;
  const int id = (int)blockIdx.x;
  const int newid = (id & 7) * cpx + (id >> 3);  // nwg % 8 == 0
  const int m0 = (newid / nx) * 128, n0 = (newid % nx) * 128;

  const f32x4 z4 = {0.f, 0.f, 0.f, 0.f};
  f32x4 acc[4][4];
#pragma unroll
  for (int m = 0; m < 4; ++m)
#pragma unroll
    for (int n = 0; n < 4; ++n) acc[m][n] = z4;

  for (int kt = 0; kt < 16; ++kt) {
    const int kbase = kt * 64;
#pragma unroll
    for (int issue = 0; issue < 4; ++issue) {
      int i = issue * 256 + tid;
      int r = i >> 3, jp = (i & 7) ^ (r & 7);  // swizzled source chunk
      gload16(A + (size_t)(m0 + r) * 1024 + kbase + jp * 8,
              lA + (size_t)(issue * 256 + (tid & ~63)) * 8);
      gload16(Bt + (size_t)(n0 + r) * 1024 + kbase + jp * 8,
              lB + (size_t)(issue * 256 + (tid & ~63)) * 8);
    }
    __syncthreads();
#pragma unroll
    for (int kk = 0; kk < 2; ++kk) {
      bf16x8 a[4], b[4];
#pragma unroll
      for (int m = 0; m < 4; ++m) {
        int row = wm * 64 + m * 16 + r16;
        int off = row * 128 + ((kk * 64 + g * 16) ^ ((r16 & 7) << 4));
        a[m] = *(const bf16x8*)((const char*)lA + off);
      }
#pragma unroll
      for (int n = 0; n < 4; ++n) {
        int row = wn * 64 + n * 16 + r16;
        int off = row * 128 + ((kk * 64 + g * 16) ^ ((r16 & 7) << 4));
        b[n] = *(const bf16x8*)((const char*)lB + off);
      }
      __builtin_amdgcn_s_setprio(1);
#pragma unroll
      for (int m = 0; m < 4; ++m)
#pragma unroll
        for (int n = 0; n < 4; ++n) acc[m][n] = mfma16(a[m], b[n], acc[m][n]);
      __builtin_amdgcn_s_setprio(0);
    }
    __syncthreads();
  }
#pragma unroll
  for (int m = 0; m < 4; ++m)
#pragma unroll
    for (int n = 0; n < 4; ++n) {
      int col = n0 + wn * 64 + n * 16 + r16;
#pragma unroll
      for (int j = 0; j < 4; ++j) {
        int row = m0 + wm * 64 + m * 16 + g * 4 + j;
        Cb[(size_t)row * N + col] = f2bf(acc[m][n][j]);
      }
    }
}

// ---------------- GEMM2: 64x64 tile (grid 4x bigger -> 4 blocks/CU) --------

__global__ __launch_bounds__(256) void gemm64(const u16* __restrict__ A,
                                              const u16* __restrict__ Bt,
                                              float* __restrict__ Cf,
                                              int N, int nx, int cpx) {
  __shared__ __align__(16) u16 lA[64 * 64];
  __shared__ __align__(16) u16 lB[64 * 64];
  const int tid = threadIdx.x;
  const int lane = tid & 63, w = tid >> 6;
  const int g = lane >> 4, r16 = lane & 15;
  const int wm = w >> 1, wn = w & 1;
  const int id = (int)blockIdx.x;
  const int newid = (id & 7) * cpx + (id >> 3);
  const int m0 = (newid / nx) * 64, n0 = (newid % nx) * 64;

  const f32x4 z4 = {0.f, 0.f, 0.f, 0.f};
  f32x4 acc[2][2];
#pragma unroll
  for (int m = 0; m < 2; ++m)
#pragma unroll
    for (int n = 0; n < 2; ++n) acc[m][n] = z4;

  for (int kt = 0; kt < 16; ++kt) {
    const int kbase = kt * 64;
#pragma unroll
    for (int issue = 0; issue < 2; ++issue) {
      int i = issue * 256 + tid;
      int r = i >> 3, jp = (i & 7) ^ (r & 7);
      gload16(A + (size_t)(m0 + r) * 1024 + kbase + jp * 8,
              lA + (size_t)(issue * 256 + (tid & ~63)) * 8);
      gload16(Bt + (size_t)(n0 + r) * 1024 + kbase + jp * 8,
              lB + (size_t)(issue * 256 + (tid & ~63)) * 8);
    }
    __syncthreads();
#pragma unroll
    for (int kk = 0; kk < 2; ++kk) {
      bf16x8 a[2], b[2];
#pragma unroll
      for (int m = 0; m < 2; ++m) {
        int row = wm * 32 + m * 16 + r16;
        int off = row * 128 + ((kk * 64 + g * 16) ^ ((r16 & 7) << 4));
        a[m] = *(const bf16x8*)((const char*)lA + off);
      }
#pragma unroll
      for (int n = 0; n < 2; ++n) {
        int row = wn * 32 + n * 16 + r16;
        int off = row * 128 + ((kk * 64 + g * 16) ^ ((r16 & 7) << 4));
        b[n] = *(const bf16x8*)((const char*)lB + off);
      }
      __builtin_amdgcn_s_setprio(1);
#pragma unroll
      for (int m = 0; m < 2; ++m)
#pragma unroll
        for (int n = 0; n < 2; ++n) acc[m][n] = mfma16(a[m], b[n], acc[m][n]);
      __builtin_amdgcn_s_setprio(0);
    }
    __syncthreads();
  }
#pragma unroll
  for (int m = 0; m < 2; ++m)
#pragma unroll
    for (int n = 0; n < 2; ++n) {
      int col = n0 + wn * 32 + n * 16 + r16;
#pragma unroll
      for (int j = 0; j < 4; ++j) {
        int row = m0 + wm * 32 + m * 16 + g * 4 + j;
        Cf[(size_t)row * N + col] = acc[m][n][j];
      }
    }
}

// ---------------- fused causal flash attention (swapped QK^T) ----------------
// Grid 1024, 4 blocks/CU (LDS 4x40KB = 160KB), balanced by construction:
// xcd=flat&7, cu=(flat>>3)&31, round=(flat>>8)&3; grp=xcd*4+round;
// qt = round&1 ? cu : 31-cu  -> each CU's 4 resident blocks sum to 66 steps.
// QBLK=64 (4 waves x 16 q-rows), KVBLK=64, dbuf K/V prefetch, in-lane softmax
// (exp2 domain), defer-max rescale (T13, THR=8).

__global__ __launch_bounds__(256) void attn_fused(const u16* __restrict__ qkv,
                                                  const u16* __restrict__ vt,
                                                  u16* __restrict__ ao) {
  __shared__ __align__(16) u16 lK[2][64 * 64];
  __shared__ __align__(16) u16 lV[2][64 * 64];
  __shared__ __align__(16) u16 lP[4][16 * 64];
  const int tid = threadIdx.x;
  const int lane = tid & 63, w = tid >> 6;
  const int g = lane >> 4, r16 = lane & 15;

  const int flat = (int)blockIdx.x;
  const int xcd = flat & 7;
  const int cu = (flat >> 3) & 31;
  const int round = (flat >> 8) & 3;
  const int grp = xcd * 4 + round;               // b*16+h
  const int qt = (round & 1) ? cu : 31 - cu;
  const int b = grp >> 4, h = grp & 15;
  const int q0w = qt * 64 + w * 16;

  // Q fragments (q-row = r16), scale*log2e folded into wqkvT
  bf16x8 aq[2];
  {
    const u16* qrow = qkv + (size_t)(b * 2048 + q0w + r16) * 3072 + h * 64;
    aq[0] = *(const bf16x8*)(qrow + g * 8);
    aq[1] = *(const bf16x8*)(qrow + 32 + g * 8);
  }

  const int r = tid >> 3, jp = (tid & 7) ^ (r & 7);  // staging decomposition
  const u16* ksrc = qkv + (size_t)(b * 2048 + r) * 3072 + 1024 + h * 64 + jp * 8;
  const u16* vsrc = vt + (size_t)((b * 16 + h) * 64 + r) * 2048 + jp * 8;
  const size_t ldst = (size_t)(tid & ~63) * 8;

  const f32x4 z4 = {0.f, 0.f, 0.f, 0.f};
  f32x4 o[4];
#pragma unroll
  for (int n = 0; n < 4; ++n) o[n] = z4;
  float mrun = -INFINITY, lrun = 0.f;

  gload16(ksrc, lK[0] + ldst);
  gload16(ksrc + (size_t)32 * 3072, lK[0] + 2048 + ldst);   // rows 32..63
  gload16(vsrc, lV[0] + ldst);
  gload16(vsrc + (size_t)32 * 2048, lV[0] + 2048 + ldst);   // rows 32..63
  __syncthreads();

  int cur = 0;
  u16* lp = lP[w];
  for (int t = 0; t <= qt; ++t) {
    if (t < qt) {  // prefetch next K/V tile into the other buffer
      const u16* kn = ksrc + (size_t)(t + 1) * 64 * 3072;
      const u16* vn = vsrc + (size_t)(t + 1) * 64;
      gload16(kn, lK[cur ^ 1] + ldst);
      gload16(kn + (size_t)32 * 3072, lK[cur ^ 1] + 2048 + ldst);
      gload16(vn, lV[cur ^ 1] + ldst);
      gload16(vn + (size_t)32 * 2048, lV[cur ^ 1] + 2048 + ldst);
    }
    // S^T = K Q^T : s[f][j] -> q = r16, kv = f*16 + g*4 + j
    f32x4 s[4];
#pragma unroll
    for (int f = 0; f < 4; ++f) s[f] = z4;
    __builtin_amdgcn_s_setprio(1);
#pragma unroll
    for (int kk = 0; kk < 2; ++kk) {
#pragma unroll
      for (int f = 0; f < 4; ++f) {
        int row = f * 16 + r16;
        int off = row * 128 + ((kk * 64 + g * 16) ^ ((r16 & 7) << 4));
        bf16x8 ak = *(const bf16x8*)((const char*)lK[cur] + off);
        s[f] = mfma16(ak, aq[kk], s[f]);  // A = K rows, B = Q rows
      }
    }
    __builtin_amdgcn_s_setprio(0);
    if (t == qt) {  // diagonal tile: causal mask (kv > q)
      const int qrel = w * 16 + r16;  // q - kv0
#pragma unroll
      for (int f = 0; f < 4; ++f)
#pragma unroll
        for (int j = 0; j < 4; ++j)
          if (f * 16 + g * 4 + j > qrel) s[f][j] = -3.0e38f;
    }
    // in-lane online softmax (exp2 domain), lane owns q-row r16
    float mx = fmaxf(fmaxf(fmaxf(s[0][0], s[0][1]), fmaxf(s[0][2], s[0][3])),
                     fmaxf(fmaxf(s[1][0], s[1][1]), fmaxf(s[1][2], s[1][3])));
    mx = fmaxf(mx, fmaxf(fmaxf(fmaxf(s[2][0], s[2][1]), fmaxf(s[2][2], s[2][3])),
                         fmaxf(fmaxf(s[3][0], s[3][1]), fmaxf(s[3][2], s[3][3]))));
    mx = fmaxf(mx, __shfl_xor(mx, 16));
    mx = fmaxf(mx, __shfl_xor(mx, 32));
    // defer-max (T13): skip the O-rescale unless some row grew past THR=8
    if (!__all(mx - mrun <= 8.0f)) {
      float mnew = fmaxf(mrun, mx);
      float corr = exp2fast(mrun - mnew);
      mrun = mnew;
      lrun *= corr;
      float cj[4];
#pragma unroll
      for (int j = 0; j < 4; ++j) cj[j] = __shfl(corr, g * 4 + j);
#pragma unroll
      for (int n = 0; n < 4; ++n)
#pragma unroll
        for (int j = 0; j < 4; ++j) o[n][j] *= cj[j];
    }
    float sm = 0.f;
#pragma unroll
    for (int f = 0; f < 4; ++f)
#pragma unroll
      for (int j = 0; j < 4; ++j) {
        s[f][j] = exp2fast(s[f][j] - mrun);
        sm += s[f][j];
      }
    sm += __shfl_xor(sm, 16);
    sm += __shfl_xor(sm, 32);
    lrun += sm;

    // P -> per-wave LDS, packed u32 (kv pairs), swizzled rows
#pragma unroll
    for (int f = 0; f < 4; ++f) {
      u32 w0 = (u32)f2bf(s[f][0]) | ((u32)f2bf(s[f][1]) << 16);
      u32 w1 = (u32)f2bf(s[f][2]) | ((u32)f2bf(s[f][3]) << 16);
      int base = r16 * 128 + ((f * 32 + g * 8) ^ ((r16 & 7) << 4));
      *(u32*)((char*)lp + base) = w0;
      *(u32*)((char*)lp + base + 4) = w1;
    }
    // PV: A = P rows (q = r16), B = V^T rows (d)
    __builtin_amdgcn_s_setprio(1);
#pragma unroll
    for (int ks = 0; ks < 2; ++ks) {
      int abyte = r16 * 128 + ((ks * 64 + g * 16) ^ ((r16 & 7) << 4));
      bf16x8 ap = *(const bf16x8*)((const char*)lp + abyte);
#pragma unroll
      for (int n = 0; n < 4; ++n) {
        int row = n * 16 + r16;
        int off = row * 128 + ((ks * 64 + g * 16) ^ ((r16 & 7) << 4));
        bf16x8 bv = *(const bf16x8*)((const char*)lV[cur] + off);
        o[n] = mfma16(ap, bv, o[n]);
      }
    }
    __builtin_amdgcn_s_setprio(0);
    __syncthreads();  // drains prefetch + protects buffer swap
    cur ^= 1;
  }
  // epilogue: O rows = q = g*4+j, cols = d = n*16+r16
  float lj[4];
#pragma unroll
  for (int j = 0; j < 4; ++j) lj[j] = __shfl(lrun, g * 4 + j);
#pragma unroll
  for (int n = 0; n < 4; ++n) {
    int col = h * 64 + n * 16 + r16;
#pragma unroll
    for (int j = 0; j < 4; ++j) {
      int row = b * 2048 + q0w + g * 4 + j;
      ao[(size_t)row * 1024 + col] = f2bf(o[n][j] * (1.f / lj[j]));
    }
  }
}

// ---------------- launch ----------------

extern "C" void kernel_launch(void* const* d_in, const int* in_sizes, int n_in,
                              void* d_out, int out_size, void* d_ws, size_t ws_size,
                              hipStream_t stream) {
  const float* x     = (const float*)d_in[0];
  // d_in[1] = attn_mask: causal tril, implemented analytically — unused.
  const float* w_qkv = (const float*)d_in[2];
  const float* w_out = (const float*)d_in[3];
  float* out = (float*)d_out;

  u16* ws = (u16*)d_ws;
  u16* x_bf  = ws;                               // 4096*1024           (4M)
  u16* wqkvT = x_bf + (size_t)4096 * 1024;       // 3072*1024           (3M)
  u16* woutT = wqkvT + (size_t)3072 * 1024;      // 1024*1024           (1M)
  u16* qkv   = woutT + (size_t)1024 * 1024;      // 4096*3072           (12M)
  u16* ao    = qkv + (size_t)4096 * 3072;        // 4096*1024           (4M)
  u16* vtb   = x_bf;                             // 2048*2048, aliases x_bf (dead after GEMM1)

  cvt_x<<<4096, 256, 0, stream>>>(x, x_bf);
  wtrans<<<dim3(48, 16), 256, 0, stream>>>(w_qkv, wqkvT, 1024, 3072, 1024);  // fold q-scale*log2e
  wtrans<<<dim3(16, 16), 256, 0, stream>>>(w_out, woutT, 1024, 1024, 0);
  gemm_bf16<<<768, 256, 0, stream>>>(x_bf, wqkvT, qkv, 3072, 24, 96);
  vtrans<<<dim3(32, 16, 2), 256, 0, stream>>>(qkv, vtb);
  attn_fused<<<1024, 256, 0, stream>>>(qkv, vtb, ao);
  gemm64<<<1024, 256, 0, stream>>>(ao, woutT, out, 1024, 16, 128);
}